// Round 5
// baseline (120.962 us; speedup 1.0000x reference)
//
#include <hip/hip_runtime.h>

// Problem constants
#define Bc  32
#define Nc  16
#define Tc  64
#define Hc  256
#define NTc 1024   // N*T

typedef unsigned short u16;
using v8s = __attribute__((ext_vector_type(8))) short;   // 8 bf16 = 4 VGPRs (MFMA A/B frag)
using v4f = __attribute__((ext_vector_type(4))) float;   // MFMA C/D frag

// fp32 -> bf16 round-to-nearest-even (inputs finite)
static __device__ __forceinline__ u16 f2bf(float x) {
    unsigned u = __float_as_uint(x);
    unsigned r = u + 0x7fffu + ((u >> 16) & 1u);
    return (u16)(r >> 16);
}
static __device__ __forceinline__ float bf2f(u16 h) {
    return __uint_as_float(((unsigned)h) << 16);
}

// ---------------------------------------------------------------------------
// Prep kernel, 544 blocks (full-chip parallel):
//  blocks [0,512): tile (b, h-chunk64, t-chunk16): mean over i with full-line
//                  256 B reads, LDS transpose, write bf16 MT[b][h][t].
//  blocks [512,544): node hi/lo bf16 split (NH/NL, [b][t][h]); zero Wsum.
// ---------------------------------------------------------------------------
__global__ __launch_bounds__(256) void prep_kernel(const float* __restrict__ neigh,
                                                   const float* __restrict__ node,
                                                   u16* __restrict__ MT,
                                                   u16* __restrict__ NH,
                                                   u16* __restrict__ NL,
                                                   float* __restrict__ Wsum) {
    __shared__ float Ls[16][68];
    int bk = blockIdx.x, tid = threadIdx.x;

    if (bk < 512) {
        int b  = bk >> 4;
        int h0 = ((bk >> 2) & 3) << 6;
        int t0 = (bk & 3) << 4;
        int t  = tid >> 4;        // 0..15
        int h4 = tid & 15;        // float4 index within the 64-h chunk
        const float4* p = (const float4*)(neigh + ((size_t)(b * Nc * Tc) + (t0 + t)) * Hc + h0) + h4;
        float4 a = make_float4(0.f, 0.f, 0.f, 0.f);
#pragma unroll
        for (int i = 0; i < Nc; i++) {
            float4 v = p[(size_t)i * (Tc * Hc / 4)];
            a.x += v.x; a.y += v.y; a.z += v.z; a.w += v.w;
        }
        const float r = 1.0f / 16.0f;
        Ls[t][h4 * 4 + 0] = a.x * r;
        Ls[t][h4 * 4 + 1] = a.y * r;
        Ls[t][h4 * 4 + 2] = a.z * r;
        Ls[t][h4 * 4 + 3] = a.w * r;
        __syncthreads();
        // transpose-write bf16: MT[b][h0+h][t0 + t4*4 .. +3]
        int h  = tid >> 2;        // 0..63
        int t4 = tid & 3;         // 0..3
        ushort4 o;
        o.x = f2bf(Ls[t4 * 4 + 0][h]);
        o.y = f2bf(Ls[t4 * 4 + 1][h]);
        o.z = f2bf(Ls[t4 * 4 + 2][h]);
        o.w = f2bf(Ls[t4 * 4 + 3][h]);
        *(ushort4*)(MT + ((size_t)b * Hc + h0 + h) * Tc + t0 + t4 * 4) = o;
    } else {
        int b = bk - 512;
#pragma unroll
        for (int rep = 0; rep < 16; rep++) {
            int idx = rep * 256 + tid;          // 4096 float4 = 64x256 floats
            int t = idx >> 6, c4 = idx & 63;
            size_t off = ((size_t)b * Tc + t) * Hc + c4 * 4;
            float4 v = *(const float4*)(node + off);
            ushort4 hs, ls;
            hs.x = f2bf(v.x); ls.x = f2bf(v.x - bf2f(hs.x));
            hs.y = f2bf(v.y); ls.y = f2bf(v.y - bf2f(hs.y));
            hs.z = f2bf(v.z); ls.z = f2bf(v.z - bf2f(hs.z));
            hs.w = f2bf(v.w); ls.w = f2bf(v.w - bf2f(hs.w));
            *(ushort4*)(NH + off) = hs;
            *(ushort4*)(NL + off) = ls;
        }
        if (tid < 64) Wsum[b * 64 + tid] = 0.f;
    }
}

// ---------------------------------------------------------------------------
// Fused MFMA kernel, direct-fragment version: block = (b, i), 4 waves.
//  Phase A (NO LDS, NO barrier): S(64x64) = X @ node^T / sqrt(nb).
//    A-frags: 2 float4 direct from neigh (L3-hot) + in-reg hi/lo bf16 split.
//    B-frags: 16 B v8s direct from precomputed NH/NL (L1/L2-hot).
//    3 MFMAs per (nt,ks): hh + hl + lh  -> fp32-grade logits.
//  Softmax in C-layout registers; column sums -> Wsum (atomic).
//  P transposed C-layout -> A-layout via LDS (the ONE barrier).
//  Phase B (NO staging): out = P @ M; B-frags 16 B v8s direct from MT[h][t].
// Frag layouts (m89/m97-verified, identical indexing to R4 which passed):
//   A/B: (m|n)=lane&15, k=quad*8+j ;  C/D: col=lane&15, row=quad*4+reg.
// ---------------------------------------------------------------------------
__global__ __launch_bounds__(256, 2) void fused_kernel(const float* __restrict__ neigh,
                                                       const u16* __restrict__ NH,
                                                       const u16* __restrict__ NL,
                                                       const int* __restrict__ nbr,
                                                       const u16* __restrict__ MT,
                                                       float* __restrict__ out,
                                                       float* __restrict__ Wsum) {
    __shared__ u16 Ph[64][72];
    __shared__ float Wtmp[256];

    int b  = blockIdx.x >> 4;
    int i  = blockIdx.x & 15;
    int q0 = i << 6;

    int tid  = threadIdx.x;
    int w    = tid >> 6;         // wave 0..3 -> q-rows w*16..w*16+15
    int lane = tid & 63;
    int quad = lane >> 4;
    int c    = lane & 15;

    // neighbors_number: int64 per reference; harness may upload int32.
    // Values in [1,16] so nbr[1]==0 <=> int64 (high word of elem 0).
    int nb = (nbr[1] == 0) ? nbr[2 * b] : nbr[b];
    float rscale = rsqrtf((float)nb);

    const float* Xrow = neigh + ((size_t)(b * Nc * Tc) + q0 + w * 16 + c) * Hc;
    const u16*   NHb  = NH + (size_t)b * Tc * Hc;
    const u16*   NLb  = NL + (size_t)b * Tc * Hc;
    const u16*   MTb  = MT + (size_t)b * Hc * Tc;

    v4f acc[4];
#pragma unroll
    for (int nt = 0; nt < 4; nt++)
#pragma unroll
        for (int rg = 0; rg < 4; rg++) acc[nt][rg] = 0.f;

    // ---- Phase A: K=256, 8 k-steps of 32, fragments direct from global ----
#pragma unroll
    for (int ks = 0; ks < Hc; ks += 32) {
        float4 f0 = *(const float4*)(Xrow + ks + quad * 8);
        float4 f1 = *(const float4*)(Xrow + ks + quad * 8 + 4);
        v8s ah, al;
        {
            u16 h0 = f2bf(f0.x), h1 = f2bf(f0.y), h2 = f2bf(f0.z), h3 = f2bf(f0.w);
            u16 h4 = f2bf(f1.x), h5 = f2bf(f1.y), h6 = f2bf(f1.z), h7 = f2bf(f1.w);
            ah[0] = (short)h0; ah[1] = (short)h1; ah[2] = (short)h2; ah[3] = (short)h3;
            ah[4] = (short)h4; ah[5] = (short)h5; ah[6] = (short)h6; ah[7] = (short)h7;
            al[0] = (short)f2bf(f0.x - bf2f(h0)); al[1] = (short)f2bf(f0.y - bf2f(h1));
            al[2] = (short)f2bf(f0.z - bf2f(h2)); al[3] = (short)f2bf(f0.w - bf2f(h3));
            al[4] = (short)f2bf(f1.x - bf2f(h4)); al[5] = (short)f2bf(f1.y - bf2f(h5));
            al[6] = (short)f2bf(f1.z - bf2f(h6)); al[7] = (short)f2bf(f1.w - bf2f(h7));
        }
#pragma unroll
        for (int nt = 0; nt < 4; nt++) {
            size_t roff = (size_t)(nt * 16 + c) * Hc + ks + quad * 8;
            v8s bh = *(const v8s*)(NHb + roff);
            v8s bl = *(const v8s*)(NLb + roff);
            acc[nt] = __builtin_amdgcn_mfma_f32_16x16x32_bf16(ah, bh, acc[nt], 0, 0, 0);
            acc[nt] = __builtin_amdgcn_mfma_f32_16x16x32_bf16(ah, bl, acc[nt], 0, 0, 0);
            acc[nt] = __builtin_amdgcn_mfma_f32_16x16x32_bf16(al, bh, acc[nt], 0, 0, 0);
        }
    }

    // ---- Softmax over t (C-layout: col = nt*16+c, row = w*16+quad*4+rg) ----
#pragma unroll
    for (int nt = 0; nt < 4; nt++)
#pragma unroll
        for (int rg = 0; rg < 4; rg++) acc[nt][rg] *= rscale;

#pragma unroll
    for (int rg = 0; rg < 4; rg++) {
        float m = fmaxf(fmaxf(acc[0][rg], acc[1][rg]), fmaxf(acc[2][rg], acc[3][rg]));
#pragma unroll
        for (int d = 1; d < 16; d <<= 1) m = fmaxf(m, __shfl_xor(m, d));
        float e0 = __expf(acc[0][rg] - m);
        float e1 = __expf(acc[1][rg] - m);
        float e2 = __expf(acc[2][rg] - m);
        float e3 = __expf(acc[3][rg] - m);
        float s = e0 + e1 + e2 + e3;
#pragma unroll
        for (int d = 1; d < 16; d <<= 1) s += __shfl_xor(s, d);
        float inv = 1.0f / s;
        acc[0][rg] = e0 * inv; acc[1][rg] = e1 * inv;
        acc[2][rg] = e2 * inv; acc[3][rg] = e3 * inv;
    }

    // Column sums for W: lane partial over its 4 rows, reduce across quads.
#pragma unroll
    for (int nt = 0; nt < 4; nt++) {
        float cs = acc[nt][0] + acc[nt][1] + acc[nt][2] + acc[nt][3];
        cs += __shfl_xor(cs, 16);
        cs += __shfl_xor(cs, 32);
        if (quad == 0) Wtmp[w * 64 + nt * 16 + c] = cs;
    }

    // P -> LDS bf16 (row = w*16+quad*4+rg, col = nt*16+c): C->A layout xpose
#pragma unroll
    for (int nt = 0; nt < 4; nt++)
#pragma unroll
        for (int rg = 0; rg < 4; rg++)
            Ph[w * 16 + quad * 4 + rg][nt * 16 + c] = f2bf(acc[nt][rg]);

    __syncthreads();   // the only barrier

    if (tid < 64) {
        float s = Wtmp[tid] + Wtmp[64 + tid] + Wtmp[128 + tid] + Wtmp[192 + tid];
        atomicAdd(&Wsum[b * Tc + tid], s);
    }

    // ---- Phase B: out = P(64x64) @ M(64x256); B-frags direct from MT ----
    v8s pa0 = *(const v8s*)&Ph[w * 16 + c][quad * 8];
    v8s pa1 = *(const v8s*)&Ph[w * 16 + c][32 + quad * 8];

    float* ob = out + ((size_t)b * NTc + q0 + w * 16 + quad * 4) * Hc + c;
#pragma unroll
    for (int ht = 0; ht < 16; ht++) {
        const u16* mr = MTb + (size_t)(ht * 16 + c) * Tc;   // h-row of MT
        v8s b0 = *(const v8s*)(mr + quad * 8);
        v8s b1 = *(const v8s*)(mr + 32 + quad * 8);
        v4f oc;
        oc[0] = 0.f; oc[1] = 0.f; oc[2] = 0.f; oc[3] = 0.f;
        oc = __builtin_amdgcn_mfma_f32_16x16x32_bf16(pa0, b0, oc, 0, 0, 0);
        oc = __builtin_amdgcn_mfma_f32_16x16x32_bf16(pa1, b1, oc, 0, 0, 0);
#pragma unroll
        for (int rg = 0; rg < 4; rg++)
            ob[(size_t)rg * Hc + ht * 16] = oc[rg];
    }
}

// ---------------------------------------------------------------------------
// W[b,i,t] = Wsum[b,t] / 16  (independent of i)
// ---------------------------------------------------------------------------
__global__ __launch_bounds__(256) void wexp_kernel(const float* __restrict__ Wsum,
                                                   float* __restrict__ Wout) {
    int idx = blockIdx.x * 256 + threadIdx.x;   // over B*N*T = 32768
    int b = idx >> 10;
    int t = idx & 63;
    Wout[idx] = Wsum[b * Tc + t] * (1.0f / 16.0f);
}

// ---------------------------------------------------------------------------
extern "C" void kernel_launch(void* const* d_in, const int* in_sizes, int n_in,
                              void* d_out, int out_size, void* d_ws, size_t ws_size,
                              hipStream_t stream) {
    const float* node  = (const float*)d_in[0];   // (B,T,H)
    const float* neigh = (const float*)d_in[1];   // (B,N,T,H)
    const int*   nbr   = (const int*)d_in[2];     // (B,) int32/int64 (detected)

    float* out = (float*)d_out;                   // (B,NT,H) then W (B,N,T)

    u16* MTw = (u16*)d_ws;                        // [B][H][T] bf16 transposed mean
    u16* NHw = MTw + (size_t)Bc * Hc * Tc;        // [B][T][H] bf16 node hi
    u16* NLw = NHw + (size_t)Bc * Tc * Hc;        // [B][T][H] bf16 node lo
    float* Ww = (float*)(NLw + (size_t)Bc * Tc * Hc);  // [B][T] fp32

    prep_kernel <<<544, 256, 0, stream>>>(neigh, node, MTw, NHw, NLw, Ww);
    fused_kernel<<<512, 256, 0, stream>>>(neigh, NHw, NLw, nbr, MTw, out, Ww);
    wexp_kernel <<<128, 256, 0, stream>>>(Ww, out + (size_t)Bc * NTc * Hc);
}

// Round 6
// 116.471 us; speedup vs baseline: 1.0386x; 1.0386x over previous
//
#include <hip/hip_runtime.h>

// Problem constants
#define Bc  32
#define Nc  16
#define Tc  64
#define Hc  256
#define NTc 1024   // N*T

typedef unsigned short u16;
using v8s = __attribute__((ext_vector_type(8))) short;   // 8 bf16 = 4 VGPRs (MFMA A/B frag)
using v4f = __attribute__((ext_vector_type(4))) float;   // MFMA C/D frag

// fp32 -> bf16 round-to-nearest-even (inputs finite)
static __device__ __forceinline__ u16 f2bf(float x) {
    unsigned u = __float_as_uint(x);
    unsigned r = u + 0x7fffu + ((u >> 16) & 1u);
    return (u16)(r >> 16);
}
static __device__ __forceinline__ float bf2f(u16 h) {
    return __uint_as_float(((unsigned)h) << 16);
}

// Fragment-major layouts (per b):
//  NHf/NLf: frag f = (nt*8 + ksb)*64 + lane, holds node[t=nt*16+c][h=ksb*32+quad*8+j]
//           j=0..7, lane=quad*16+c.  One wave B-load = 1KB contiguous.
//  MTf:     frag f = (ht*2 + ktb)*64 + lane, holds M[t=ktb*32+quad*8+j][h=ht*16+c]
#define NFRAG_NODE 2048   // 4nt * 8ksb * 64lane
#define NFRAG_MT   2048   // 16ht * 2ktb * 64lane

// ---------------------------------------------------------------------------
// Prep kernel, 544 blocks:
//  blocks [0,512): (b, h-chunk16): mean over i -> LDS tile -> MTf frags.
//  blocks [512,544): node hi/lo bf16 split in fragment-major order; zero Wsum.
// ---------------------------------------------------------------------------
__global__ __launch_bounds__(256) void prep_kernel(const float* __restrict__ neigh,
                                                   const float* __restrict__ node,
                                                   u16* __restrict__ MTf,
                                                   u16* __restrict__ NHf,
                                                   u16* __restrict__ NLf,
                                                   float* __restrict__ Wsum) {
    __shared__ float Ls[64][17];   // [t][h_local], +1 pad
    int bk = blockIdx.x, tid = threadIdx.x;

    if (bk < 512) {
        int b  = bk >> 4;
        int hc = bk & 15;          // 16-h chunk id (== ht tile id)
        int h0 = hc << 4;
        // mean over i: thread (t = tid>>2, h4 = tid&3) sums float4
        int t  = tid >> 2;
        int h4 = tid & 3;
        const float4* p = (const float4*)(neigh + ((size_t)(b * Nc * Tc) + t) * Hc + h0) + h4;
        float4 a = make_float4(0.f, 0.f, 0.f, 0.f);
#pragma unroll
        for (int i = 0; i < Nc; i++) {
            float4 v = p[(size_t)i * (Tc * Hc / 4)];
            a.x += v.x; a.y += v.y; a.z += v.z; a.w += v.w;
        }
        const float r = 1.0f / 16.0f;
        Ls[t][h4 * 4 + 0] = a.x * r;
        Ls[t][h4 * 4 + 1] = a.y * r;
        Ls[t][h4 * 4 + 2] = a.z * r;
        Ls[t][h4 * 4 + 3] = a.w * r;
        __syncthreads();
        // write 128 MTf frags for this (b, ht=hc): tid<128
        if (tid < 128) {
            int ktb  = tid >> 6;
            int lane = tid & 63;
            int quad = lane >> 4;
            int c    = lane & 15;
            v8s o;
#pragma unroll
            for (int j = 0; j < 8; j++)
                o[j] = (short)f2bf(Ls[ktb * 32 + quad * 8 + j][c]);
            *(v8s*)(MTf + ((size_t)b * NFRAG_MT + (hc * 2 + ktb) * 64 + lane) * 8) = o;
        }
    } else {
        int b = bk - 512;
#pragma unroll
        for (int rep = 0; rep < 8; rep++) {
            int f    = rep * 256 + tid;       // 0..2047
            int nt   = f >> 9;
            int ksb  = (f >> 6) & 7;
            int lane = f & 63;
            int quad = lane >> 4;
            int c    = lane & 15;
            const float* src = node + ((size_t)b * Tc + nt * 16 + c) * Hc + ksb * 32 + quad * 8;
            float4 f0 = *(const float4*)(src);
            float4 f1 = *(const float4*)(src + 4);
            v8s hs, ls;
            float vin[8] = {f0.x, f0.y, f0.z, f0.w, f1.x, f1.y, f1.z, f1.w};
#pragma unroll
            for (int j = 0; j < 8; j++) {
                u16 h = f2bf(vin[j]);
                hs[j] = (short)h;
                ls[j] = (short)f2bf(vin[j] - bf2f(h));
            }
            *(v8s*)(NHf + ((size_t)b * NFRAG_NODE + f) * 8) = hs;
            *(v8s*)(NLf + ((size_t)b * NFRAG_NODE + f) * 8) = ls;
        }
        if (tid < 64) Wsum[b * 64 + tid] = 0.f;
    }
}

// ---------------------------------------------------------------------------
// Fused MFMA kernel: block = (b, i), 4 waves, ONE barrier, NO staging.
//  Phase A: S(64x64) = X @ node^T / sqrt(nb); A-frags direct from neigh
//    (lane's own row, hi/lo split in-reg); B-frags = single coalesced 1KB
//    wave-loads from fragment-major NHf/NLf.  3 MFMAs (hh+hl+lh) per step.
//  Softmax in C-layout regs; column sums -> Wsum; P -> LDS (C->A transpose).
//  Phase B: out = P @ M; B-frags coalesced from fragment-major MTf.
// Frag layouts (m89/m97-verified): A/B (m|n)=lane&15, k=quad*8+j;
//                                  C/D col=lane&15, row=quad*4+reg.
// ---------------------------------------------------------------------------
__global__ __launch_bounds__(256) void fused_kernel(const float* __restrict__ neigh,
                                                    const u16* __restrict__ NHf,
                                                    const u16* __restrict__ NLf,
                                                    const int* __restrict__ nbr,
                                                    const u16* __restrict__ MTf,
                                                    float* __restrict__ out,
                                                    float* __restrict__ Wsum) {
    __shared__ u16 Ph[64][72];
    __shared__ float Wtmp[256];

    int b  = blockIdx.x >> 4;
    int i  = blockIdx.x & 15;
    int q0 = i << 6;

    int tid  = threadIdx.x;
    int w    = tid >> 6;
    int lane = tid & 63;
    int quad = lane >> 4;
    int c    = lane & 15;

    // neighbors_number: int64 per reference; harness may upload int32.
    // Values in [1,16] so nbr[1]==0 <=> int64 (high word of elem 0).
    int nb = (nbr[1] == 0) ? nbr[2 * b] : nbr[b];
    float rscale = rsqrtf((float)nb);

    const float* Xrow = neigh + ((size_t)(b * Nc * Tc) + q0 + w * 16 + c) * Hc;
    const u16*   NHb  = NHf + (size_t)b * NFRAG_NODE * 8 + lane * 8;
    const u16*   NLb  = NLf + (size_t)b * NFRAG_NODE * 8 + lane * 8;
    const u16*   MTb  = MTf + (size_t)b * NFRAG_MT   * 8 + lane * 8;

    v4f acc[4];
#pragma unroll
    for (int nt = 0; nt < 4; nt++)
#pragma unroll
        for (int rg = 0; rg < 4; rg++) acc[nt][rg] = 0.f;

    // ---- Phase A: K=256, 8 k-steps of 32 ----
#pragma unroll
    for (int ksb = 0; ksb < 8; ksb++) {
        float4 f0 = *(const float4*)(Xrow + ksb * 32 + quad * 8);
        float4 f1 = *(const float4*)(Xrow + ksb * 32 + quad * 8 + 4);
        v8s ah, al;
        {
            float vin[8] = {f0.x, f0.y, f0.z, f0.w, f1.x, f1.y, f1.z, f1.w};
#pragma unroll
            for (int j = 0; j < 8; j++) {
                u16 h = f2bf(vin[j]);
                ah[j] = (short)h;
                al[j] = (short)f2bf(vin[j] - bf2f(h));
            }
        }
#pragma unroll
        for (int nt = 0; nt < 4; nt++) {
            size_t foff = (size_t)((nt * 8 + ksb) * 64) * 8;
            v8s bh = *(const v8s*)(NHb + foff);
            v8s bl = *(const v8s*)(NLb + foff);
            acc[nt] = __builtin_amdgcn_mfma_f32_16x16x32_bf16(ah, bh, acc[nt], 0, 0, 0);
            acc[nt] = __builtin_amdgcn_mfma_f32_16x16x32_bf16(ah, bl, acc[nt], 0, 0, 0);
            acc[nt] = __builtin_amdgcn_mfma_f32_16x16x32_bf16(al, bh, acc[nt], 0, 0, 0);
        }
    }

    // ---- Softmax over t (C-layout: col = nt*16+c, row = w*16+quad*4+rg) ----
#pragma unroll
    for (int nt = 0; nt < 4; nt++)
#pragma unroll
        for (int rg = 0; rg < 4; rg++) acc[nt][rg] *= rscale;

#pragma unroll
    for (int rg = 0; rg < 4; rg++) {
        float m = fmaxf(fmaxf(acc[0][rg], acc[1][rg]), fmaxf(acc[2][rg], acc[3][rg]));
#pragma unroll
        for (int d = 1; d < 16; d <<= 1) m = fmaxf(m, __shfl_xor(m, d));
        float e0 = __expf(acc[0][rg] - m);
        float e1 = __expf(acc[1][rg] - m);
        float e2 = __expf(acc[2][rg] - m);
        float e3 = __expf(acc[3][rg] - m);
        float s = e0 + e1 + e2 + e3;
#pragma unroll
        for (int d = 1; d < 16; d <<= 1) s += __shfl_xor(s, d);
        float inv = 1.0f / s;
        acc[0][rg] = e0 * inv; acc[1][rg] = e1 * inv;
        acc[2][rg] = e2 * inv; acc[3][rg] = e3 * inv;
    }

    // Column sums for W.
#pragma unroll
    for (int nt = 0; nt < 4; nt++) {
        float cs = acc[nt][0] + acc[nt][1] + acc[nt][2] + acc[nt][3];
        cs += __shfl_xor(cs, 16);
        cs += __shfl_xor(cs, 32);
        if (quad == 0) Wtmp[w * 64 + nt * 16 + c] = cs;
    }

    // P -> LDS bf16 (C->A layout transpose)
#pragma unroll
    for (int nt = 0; nt < 4; nt++)
#pragma unroll
        for (int rg = 0; rg < 4; rg++)
            Ph[w * 16 + quad * 4 + rg][nt * 16 + c] = f2bf(acc[nt][rg]);

    __syncthreads();   // the only barrier

    if (tid < 64) {
        float s = Wtmp[tid] + Wtmp[64 + tid] + Wtmp[128 + tid] + Wtmp[192 + tid];
        atomicAdd(&Wsum[b * Tc + tid], s);
    }

    // ---- Phase B: out = P(64x64) @ M(64x256); B-frags coalesced from MTf ----
    v8s pa0 = *(const v8s*)&Ph[w * 16 + c][quad * 8];
    v8s pa1 = *(const v8s*)&Ph[w * 16 + c][32 + quad * 8];

    float* ob = out + ((size_t)b * NTc + q0 + w * 16 + quad * 4) * Hc + c;
#pragma unroll
    for (int ht = 0; ht < 16; ht++) {
        v8s b0 = *(const v8s*)(MTb + (size_t)((ht * 2 + 0) * 64) * 8);
        v8s b1 = *(const v8s*)(MTb + (size_t)((ht * 2 + 1) * 64) * 8);
        v4f oc;
        oc[0] = 0.f; oc[1] = 0.f; oc[2] = 0.f; oc[3] = 0.f;
        oc = __builtin_amdgcn_mfma_f32_16x16x32_bf16(pa0, b0, oc, 0, 0, 0);
        oc = __builtin_amdgcn_mfma_f32_16x16x32_bf16(pa1, b1, oc, 0, 0, 0);
#pragma unroll
        for (int rg = 0; rg < 4; rg++)
            ob[(size_t)rg * Hc + ht * 16] = oc[rg];
    }
}

// ---------------------------------------------------------------------------
// W[b,i,t] = Wsum[b,t] / 16  (independent of i)
// ---------------------------------------------------------------------------
__global__ __launch_bounds__(256) void wexp_kernel(const float* __restrict__ Wsum,
                                                   float* __restrict__ Wout) {
    int idx = blockIdx.x * 256 + threadIdx.x;   // over B*N*T = 32768
    int b = idx >> 10;
    int t = idx & 63;
    Wout[idx] = Wsum[b * Tc + t] * (1.0f / 16.0f);
}

// ---------------------------------------------------------------------------
extern "C" void kernel_launch(void* const* d_in, const int* in_sizes, int n_in,
                              void* d_out, int out_size, void* d_ws, size_t ws_size,
                              hipStream_t stream) {
    const float* node  = (const float*)d_in[0];   // (B,T,H)
    const float* neigh = (const float*)d_in[1];   // (B,N,T,H)
    const int*   nbr   = (const int*)d_in[2];     // (B,) int32/int64 (detected)

    float* out = (float*)d_out;                   // (B,NT,H) then W (B,N,T)

    u16* MTw = (u16*)d_ws;                              // [B][2048 frags][8]
    u16* NHw = MTw + (size_t)Bc * NFRAG_MT * 8;         // [B][2048 frags][8]
    u16* NLw = NHw + (size_t)Bc * NFRAG_NODE * 8;       // [B][2048 frags][8]
    float* Ww = (float*)(NLw + (size_t)Bc * NFRAG_NODE * 8);  // [B][T]

    prep_kernel <<<544, 256, 0, stream>>>(neigh, node, MTw, NHw, NLw, Ww);
    fused_kernel<<<512, 256, 0, stream>>>(neigh, NHw, NLw, nbr, MTw, out, Ww);
    wexp_kernel <<<128, 256, 0, stream>>>(Ww, out + (size_t)Bc * NTc * Hc);
}

// Round 7
// 111.491 us; speedup vs baseline: 1.0849x; 1.0447x over previous
//
#include <hip/hip_runtime.h>

// Problem constants
#define Bc  32
#define Nc  16
#define Tc  64
#define Hc  256
#define NTc 1024   // N*T

typedef unsigned short u16;
using v8s = __attribute__((ext_vector_type(8))) short;   // 8 bf16 = 4 VGPRs (MFMA A/B frag)
using v4f = __attribute__((ext_vector_type(4))) float;   // MFMA C/D frag

// fp32 -> bf16 round-to-nearest-even (inputs finite)
static __device__ __forceinline__ u16 f2bf(float x) {
    unsigned u = __float_as_uint(x);
    unsigned r = u + 0x7fffu + ((u >> 16) & 1u);
    return (u16)(r >> 16);
}
static __device__ __forceinline__ float bf2f(u16 h) {
    return __uint_as_float(((unsigned)h) << 16);
}

// Fragment-major layouts (per b):
//  NHf/NLf: frag f = (nt*8 + ksb)*64 + lane, holds node[t=nt*16+c][h=ksb*32+quad*8+j]
//           j=0..7, lane=quad*16+c.  One wave B-load = 1KB contiguous.
//  MTf:     frag f = (ht*2 + ktb)*64 + lane, holds M[t=ktb*32+quad*8+j][h=ht*16+c]
#define NFRAG_NODE 2048   // 4nt * 8ksb * 64lane
#define NFRAG_MT   2048   // 16ht * 2ktb * 64lane

// ---------------------------------------------------------------------------
// Prep kernel, 544 blocks (identical to R6 — measured fast):
//  blocks [0,512): (b, h-chunk16): mean over i -> LDS tile -> MTf frags.
//  blocks [512,544): node hi/lo bf16 split in fragment-major order; zero Wsum.
// ---------------------------------------------------------------------------
__global__ __launch_bounds__(256) void prep_kernel(const float* __restrict__ neigh,
                                                   const float* __restrict__ node,
                                                   u16* __restrict__ MTf,
                                                   u16* __restrict__ NHf,
                                                   u16* __restrict__ NLf,
                                                   float* __restrict__ Wsum) {
    __shared__ float Ls[64][17];   // [t][h_local], +1 pad
    int bk = blockIdx.x, tid = threadIdx.x;

    if (bk < 512) {
        int b  = bk >> 4;
        int hc = bk & 15;          // 16-h chunk id (== ht tile id)
        int h0 = hc << 4;
        int t  = tid >> 2;
        int h4 = tid & 3;
        const float4* p = (const float4*)(neigh + ((size_t)(b * Nc * Tc) + t) * Hc + h0) + h4;
        float4 a = make_float4(0.f, 0.f, 0.f, 0.f);
#pragma unroll
        for (int i = 0; i < Nc; i++) {
            float4 v = p[(size_t)i * (Tc * Hc / 4)];
            a.x += v.x; a.y += v.y; a.z += v.z; a.w += v.w;
        }
        const float r = 1.0f / 16.0f;
        Ls[t][h4 * 4 + 0] = a.x * r;
        Ls[t][h4 * 4 + 1] = a.y * r;
        Ls[t][h4 * 4 + 2] = a.z * r;
        Ls[t][h4 * 4 + 3] = a.w * r;
        __syncthreads();
        if (tid < 128) {
            int ktb  = tid >> 6;
            int lane = tid & 63;
            int quad = lane >> 4;
            int c    = lane & 15;
            v8s o;
#pragma unroll
            for (int j = 0; j < 8; j++)
                o[j] = (short)f2bf(Ls[ktb * 32 + quad * 8 + j][c]);
            *(v8s*)(MTf + ((size_t)b * NFRAG_MT + (hc * 2 + ktb) * 64 + lane) * 8) = o;
        }
    } else {
        int b = bk - 512;
#pragma unroll
        for (int rep = 0; rep < 8; rep++) {
            int f    = rep * 256 + tid;       // 0..2047
            int nt   = f >> 9;
            int ksb  = (f >> 6) & 7;
            int lane = f & 63;
            int quad = lane >> 4;
            int c    = lane & 15;
            const float* src = node + ((size_t)b * Tc + nt * 16 + c) * Hc + ksb * 32 + quad * 8;
            float4 f0 = *(const float4*)(src);
            float4 f1 = *(const float4*)(src + 4);
            v8s hs, ls;
            float vin[8] = {f0.x, f0.y, f0.z, f0.w, f1.x, f1.y, f1.z, f1.w};
#pragma unroll
            for (int j = 0; j < 8; j++) {
                u16 h = f2bf(vin[j]);
                hs[j] = (short)h;
                ls[j] = (short)f2bf(vin[j] - bf2f(h));
            }
            *(v8s*)(NHf + ((size_t)b * NFRAG_NODE + f) * 8) = hs;
            *(v8s*)(NLf + ((size_t)b * NFRAG_NODE + f) * 8) = ls;
        }
        if (tid < 64) Wsum[b * 64 + tid] = 0.f;
    }
}

// ---------------------------------------------------------------------------
// Fused MFMA kernel: block = (b, i), 4 waves, ONE barrier.
//  Stage node-hi frags (32 KB, frag-major) into LDS once -> barrier.
//  Phase A: A-frags direct from neigh (lane's own row, hi/lo split in-reg);
//    B-hi from LDS (ds_read_b128 broadcast pipe), B-lo direct from global
//    frag-major NLf (parallel VMEM pipe, L1-hot).  3 MFMAs (hh+hl+lh).
//  Softmax in C-layout regs; per-wave column sums -> Wsum atomics (async);
//  P C->A transpose through wave-private LDS band (NO barrier needed).
//  Phase B: out = P @ M; B-frags coalesced from fragment-major MTf (L1-hot).
// Frag layouts (m89/m97-verified): A/B (m|n)=lane&15, k=quad*8+j;
//                                  C/D col=lane&15, row=quad*4+reg.
// LDS = 32 KB NHs + 9.2 KB Ph = 41 KB -> 2+ blocks/CU.
// ---------------------------------------------------------------------------
__global__ __launch_bounds__(256) void fused_kernel(const float* __restrict__ neigh,
                                                    const u16* __restrict__ NHf,
                                                    const u16* __restrict__ NLf,
                                                    const int* __restrict__ nbr,
                                                    const u16* __restrict__ MTf,
                                                    float* __restrict__ out,
                                                    float* __restrict__ Wsum) {
    __shared__ u16 NHs[NFRAG_NODE * 8];   // 32 KB, flat frag-major
    __shared__ u16 Ph[64][72];            // P bf16, wave-private 16-row bands

    int b  = blockIdx.x >> 4;
    int i  = blockIdx.x & 15;
    int q0 = i << 6;

    int tid  = threadIdx.x;
    int w    = tid >> 6;
    int lane = tid & 63;
    int quad = lane >> 4;
    int c    = lane & 15;

    // neighbors_number: int64 per reference; harness may upload int32.
    // Values in [1,16] so nbr[1]==0 <=> int64 (high word of elem 0).
    int nb = (nbr[1] == 0) ? nbr[2 * b] : nbr[b];
    float rscale = rsqrtf((float)nb);

    const float* Xrow = neigh + ((size_t)(b * Nc * Tc) + q0 + w * 16 + c) * Hc;
    const u16*   NHb  = NHf + (size_t)b * NFRAG_NODE * 8;
    const u16*   NLb  = NLf + (size_t)b * NFRAG_NODE * 8 + lane * 8;
    const u16*   MTb  = MTf + (size_t)b * NFRAG_MT   * 8 + lane * 8;

    // ---- Stage node-hi frags into LDS (one cooperative 32 KB copy) ----
#pragma unroll
    for (int rep = 0; rep < 8; rep++) {
        int chunk = rep * 256 + tid;          // 2048 x 16 B
        *(uint4*)&NHs[chunk * 8] = *(const uint4*)(NHb + chunk * 8);
    }
    __syncthreads();   // the only barrier

    v4f acc[4];
#pragma unroll
    for (int nt = 0; nt < 4; nt++)
#pragma unroll
        for (int rg = 0; rg < 4; rg++) acc[nt][rg] = 0.f;

    // ---- Phase A: K=256, 8 k-steps of 32 ----
#pragma unroll
    for (int ksb = 0; ksb < 8; ksb++) {
        float4 f0 = *(const float4*)(Xrow + ksb * 32 + quad * 8);
        float4 f1 = *(const float4*)(Xrow + ksb * 32 + quad * 8 + 4);
        v8s ah, al;
        {
            float vin[8] = {f0.x, f0.y, f0.z, f0.w, f1.x, f1.y, f1.z, f1.w};
#pragma unroll
            for (int j = 0; j < 8; j++) {
                u16 h = f2bf(vin[j]);
                ah[j] = (short)h;
                al[j] = (short)f2bf(vin[j] - bf2f(h));
            }
        }
#pragma unroll
        for (int nt = 0; nt < 4; nt++) {
            int fbase = (nt * 8 + ksb) * 64;
            v8s bh = *(const v8s*)&NHs[(fbase + lane) * 8];
            v8s bl = *(const v8s*)(NLb + (size_t)fbase * 8);
            acc[nt] = __builtin_amdgcn_mfma_f32_16x16x32_bf16(ah, bh, acc[nt], 0, 0, 0);
            acc[nt] = __builtin_amdgcn_mfma_f32_16x16x32_bf16(ah, bl, acc[nt], 0, 0, 0);
            acc[nt] = __builtin_amdgcn_mfma_f32_16x16x32_bf16(al, bh, acc[nt], 0, 0, 0);
        }
    }

    // ---- Softmax over t (C-layout: col = nt*16+c, row = w*16+quad*4+rg) ----
#pragma unroll
    for (int nt = 0; nt < 4; nt++)
#pragma unroll
        for (int rg = 0; rg < 4; rg++) acc[nt][rg] *= rscale;

#pragma unroll
    for (int rg = 0; rg < 4; rg++) {
        float m = fmaxf(fmaxf(acc[0][rg], acc[1][rg]), fmaxf(acc[2][rg], acc[3][rg]));
#pragma unroll
        for (int d = 1; d < 16; d <<= 1) m = fmaxf(m, __shfl_xor(m, d));
        float e0 = __expf(acc[0][rg] - m);
        float e1 = __expf(acc[1][rg] - m);
        float e2 = __expf(acc[2][rg] - m);
        float e3 = __expf(acc[3][rg] - m);
        float s = e0 + e1 + e2 + e3;
#pragma unroll
        for (int d = 1; d < 16; d <<= 1) s += __shfl_xor(s, d);
        float inv = 1.0f / s;
        acc[0][rg] = e0 * inv; acc[1][rg] = e1 * inv;
        acc[2][rg] = e2 * inv; acc[3][rg] = e3 * inv;
    }

    // Column sums -> global atomics (per wave, fire-and-forget).
#pragma unroll
    for (int nt = 0; nt < 4; nt++) {
        float cs = acc[nt][0] + acc[nt][1] + acc[nt][2] + acc[nt][3];
        cs += __shfl_xor(cs, 16);
        cs += __shfl_xor(cs, 32);
        if (quad == 0) atomicAdd(&Wsum[b * Tc + nt * 16 + c], cs);
    }

    // P -> wave-private LDS band (C->A transpose, intra-wave: no barrier)
#pragma unroll
    for (int nt = 0; nt < 4; nt++)
#pragma unroll
        for (int rg = 0; rg < 4; rg++)
            Ph[w * 16 + quad * 4 + rg][nt * 16 + c] = f2bf(acc[nt][rg]);

    v8s pa0 = *(const v8s*)&Ph[w * 16 + c][quad * 8];
    v8s pa1 = *(const v8s*)&Ph[w * 16 + c][32 + quad * 8];

    // ---- Phase B: out = P(64x64) @ M(64x256); B-frags coalesced from MTf ----
    float* ob = out + ((size_t)b * NTc + q0 + w * 16 + quad * 4) * Hc + c;
#pragma unroll
    for (int ht = 0; ht < 16; ht++) {
        v8s b0 = *(const v8s*)(MTb + (size_t)((ht * 2 + 0) * 64) * 8);
        v8s b1 = *(const v8s*)(MTb + (size_t)((ht * 2 + 1) * 64) * 8);
        v4f oc;
        oc[0] = 0.f; oc[1] = 0.f; oc[2] = 0.f; oc[3] = 0.f;
        oc = __builtin_amdgcn_mfma_f32_16x16x32_bf16(pa0, b0, oc, 0, 0, 0);
        oc = __builtin_amdgcn_mfma_f32_16x16x32_bf16(pa1, b1, oc, 0, 0, 0);
#pragma unroll
        for (int rg = 0; rg < 4; rg++)
            ob[(size_t)rg * Hc + ht * 16] = oc[rg];
    }
}

// ---------------------------------------------------------------------------
// W[b,i,t] = Wsum[b,t] / 16  (independent of i)
// ---------------------------------------------------------------------------
__global__ __launch_bounds__(256) void wexp_kernel(const float* __restrict__ Wsum,
                                                   float* __restrict__ Wout) {
    int idx = blockIdx.x * 256 + threadIdx.x;   // over B*N*T = 32768
    int b = idx >> 10;
    int t = idx & 63;
    Wout[idx] = Wsum[b * Tc + t] * (1.0f / 16.0f);
}

// ---------------------------------------------------------------------------
extern "C" void kernel_launch(void* const* d_in, const int* in_sizes, int n_in,
                              void* d_out, int out_size, void* d_ws, size_t ws_size,
                              hipStream_t stream) {
    const float* node  = (const float*)d_in[0];   // (B,T,H)
    const float* neigh = (const float*)d_in[1];   // (B,N,T,H)
    const int*   nbr   = (const int*)d_in[2];     // (B,) int32/int64 (detected)

    float* out = (float*)d_out;                   // (B,NT,H) then W (B,N,T)

    u16* MTw = (u16*)d_ws;                              // [B][2048 frags][8]
    u16* NHw = MTw + (size_t)Bc * NFRAG_MT * 8;         // [B][2048 frags][8]
    u16* NLw = NHw + (size_t)Bc * NFRAG_NODE * 8;       // [B][2048 frags][8]
    float* Ww = (float*)(NLw + (size_t)Bc * NFRAG_NODE * 8);  // [B][T]

    prep_kernel <<<544, 256, 0, stream>>>(neigh, node, MTw, NHw, NLw, Ww);
    fused_kernel<<<512, 256, 0, stream>>>(neigh, NHw, NLw, nbr, MTw, out, Ww);
    wexp_kernel <<<128, 256, 0, stream>>>(Ww, out + (size_t)Bc * NTc * Hc);
}